// Round 4
// baseline (683.461 us; speedup 1.0000x reference)
//
#include <hip/hip_runtime.h>
#include <hip/hip_bf16.h>

#define T_TOT   4096
#define NH      32
#define NKV     8
#define GQ      4
#define DHEAD   128
#define NSLOTS  8192
#define QB      64      // q rows per block
#define QW      32      // q rows per wave
#define KVB     64      // keys per kv tile
#define NTILES  (T_TOT / KVB)   // 64 global token tiles
// (1/sqrt(128)) * log2(e): fold scale + exp->exp2 conversion into Q
#define ATT_SCALE_L2E 0.1275174394375425f

typedef __attribute__((ext_vector_type(8))) short bf16x8;
typedef __attribute__((ext_vector_type(4))) float f32x4;

__device__ __forceinline__ unsigned short f2bf(float f) {
    union { float f; unsigned u; } x; x.f = f;
    unsigned r = x.u + 0x7fffu + ((x.u >> 16) & 1u);
    return (unsigned short)(r >> 16);
}

__device__ __forceinline__ unsigned long long pack4bf(float a, float b, float c, float d) {
    unsigned lo = (unsigned)f2bf(a) | ((unsigned)f2bf(b) << 16);
    unsigned hi = (unsigned)f2bf(c) | ((unsigned)f2bf(d) << 16);
    return (unsigned long long)lo | ((unsigned long long)hi << 32);
}

__device__ __forceinline__ void gload16(const char* g, char* l) {
    __builtin_amdgcn_global_load_lds(
        (const __attribute__((address_space(1))) void*)g,
        (__attribute__((address_space(3))) void*)l,
        16, 0, 0);
}

// Balanced-pair schedule: idx 0..31 = work descending, idx 32..63 = ascending.
// CU hosting bid c and c+256 gets desc[i] + asc[i] ~= constant (17-19 tiles).
__constant__ unsigned char QORD[64] = {
    47,46,15,45,63,14,44,62,13,29,43,61,12,28,42,60,
    11,27,41,59,10,26,40,58, 9,25,39,57, 8,24,38,56,
    48,30,16, 0,49,31,17, 1,50,32,18, 2,51,33,19, 3,
    52,34,20, 4,53,35,21, 5,54,36,22, 6,55,37,23, 7
};

// ---------------- cache copy + scatter (run AFTER attn) ----------------

__global__ __launch_bounds__(256) void copy_cache(const float4* __restrict__ kc,
                                                  const float4* __restrict__ vc,
                                                  float4* __restrict__ kco,
                                                  float4* __restrict__ vco) {
    int idx = blockIdx.x * 256 + threadIdx.x;
    kco[idx] = kc[idx];
    vco[idx] = vc[idx];
}

__global__ __launch_bounds__(256) void scatter_kv(const float4* __restrict__ k,
                                                  const float4* __restrict__ v,
                                                  const int* __restrict__ slot_map,
                                                  float4* __restrict__ kco,
                                                  float4* __restrict__ vco) {
    int idx = blockIdx.x * 256 + threadIdx.x;
    int tok = idx >> 8;
    int j   = idx & 255;
    int slot = slot_map[tok];
    if (slot >= 0 && slot < NSLOTS) {
        size_t dst = (size_t)slot * 256 + j;
        kco[dst] = k[idx];
        vco[dst] = v[idx];
    }
}

// ---------------- pre-pass: f32 K/V -> pre-swizzled bf16 tiles ----------------
// Kbf tile (16KB): key*256 + ((d4*8) ^ ((key&7)<<4))   [64 keys x 128 d]
// Vbf tile (16KB): d*128   + ((kq*8) ^ ((d&7)<<4))     [128 d x 64 keys], kq=key/4

__global__ __launch_bounds__(256) void prep_kv(const float* __restrict__ kg,
                                               const float* __restrict__ vg,
                                               char* __restrict__ kbf,
                                               char* __restrict__ vbf) {
    const int tile = blockIdx.x;
    const int kvh  = blockIdx.y;
    const int tid  = threadIdx.x;
    char* kt = kbf + (((size_t)kvh * NTILES + tile) << 14);
    char* vt = vbf + (((size_t)kvh * NTILES + tile) << 14);
    #pragma unroll
    for (int it = 0; it < 8; ++it) {
        int idx = tid + it * 256;
        int key = idx >> 5, d4 = idx & 31;
        float4 x = *(const float4*)(kg +
            ((size_t)(tile * 64 + key) * NKV + kvh) * DHEAD + d4 * 4);
        *(unsigned long long*)(kt + key * 256 + ((d4 * 8) ^ ((key & 7) << 4))) =
            pack4bf(x.x, x.y, x.z, x.w);
    }
    #pragma unroll
    for (int it = 0; it < 8; ++it) {
        int job = tid + it * 256;
        int kq = job >> 7, d = job & 127;
        const float* vp = vg +
            ((size_t)(tile * 64 + kq * 4) * NKV + kvh) * DHEAD + d;
        *(unsigned long long*)(vt + d * 128 + ((kq * 8) ^ ((d & 7) << 4))) =
            pack4bf(vp[0], vp[NKV * DHEAD], vp[2 * NKV * DHEAD], vp[3 * NKV * DHEAD]);
    }
}

// ---------------- flash attention ----------------

__global__ __launch_bounds__(512, 4) void attn_kernel(const float* __restrict__ qg,
                                                      const char* __restrict__ kbf,
                                                      const char* __restrict__ vbf,
                                                      const int* __restrict__ cu,
                                                      float* __restrict__ outg)
{
    __shared__ __align__(16) char Klds[2][KVB * 256];   // 2 x 16KB
    __shared__ __align__(16) char Vt[2][DHEAD * 128];   // 2 x 16KB
    __shared__ __align__(16) char Plds[8][16 * 128];    // 16KB (2KB/wave)

    const int tid  = threadIdx.x;
    const int wave = tid >> 6;
    const int lane = tid & 63;
    const int q16  = lane & 15;
    const int grp  = lane >> 4;
    const int bid  = blockIdx.x;
    const int qblk = QORD[bid >> 3];
    const int kvh  = bid & 7;
    const int head = kvh * GQ + (wave >> 1);
    const int tok0 = qblk * QB;
    const int qw0  = tok0 + (wave & 1) * QW;

    int seq_start = 0;
    #pragma unroll
    for (int b = 0; b < 4; ++b) {
        int c0 = cu[b], c1 = cu[b + 1];
        if (tok0 >= c0 && tok0 < c1) seq_start = c0;
    }
    const int p0  = tok0 - seq_start;
    const int pw0 = p0 + (wave & 1) * QW;
    const int ntiles = p0 / KVB + 1;
    const int tile0 = seq_start >> 6;
    const size_t tbase = (size_t)kvh * NTILES + tile0;

    // Q fragments, pre-scaled by scale*log2e (QK^T scores land in log2 domain)
    bf16x8 qf[2][4];
    {
        const float* qp = qg + ((size_t)(qw0 + q16) * NH + head) * DHEAD + grp * 8;
        #pragma unroll
        for (int qt = 0; qt < 2; ++qt) {
            #pragma unroll
            for (int c = 0; c < 4; ++c) {
                const float* p = qp + (size_t)qt * 16 * NH * DHEAD + c * 32;
                float4 a = *(const float4*)(p);
                float4 b = *(const float4*)(p + 4);
                union { bf16x8 v; unsigned long long q[2]; } u;
                u.q[0] = pack4bf(a.x * ATT_SCALE_L2E, a.y * ATT_SCALE_L2E,
                                 a.z * ATT_SCALE_L2E, a.w * ATT_SCALE_L2E);
                u.q[1] = pack4bf(b.x * ATT_SCALE_L2E, b.y * ATT_SCALE_L2E,
                                 b.z * ATT_SCALE_L2E, b.w * ATT_SCALE_L2E);
                qf[qt][c] = u.v;
            }
        }
    }

    f32x4 oacc[2][8];
    #pragma unroll
    for (int qt = 0; qt < 2; ++qt)
        #pragma unroll
        for (int n = 0; n < 8; ++n) oacc[qt][n] = (f32x4){0.f, 0.f, 0.f, 0.f};
    float mrow[2][4], lrow[2][4];   // lrow = per-lane PARTIAL sums (reduced at end)
    #pragma unroll
    for (int qt = 0; qt < 2; ++qt)
        #pragma unroll
        for (int r = 0; r < 4; ++r) { mrow[qt][r] = -1e30f; lrow[qt][r] = 0.f; }

    char* Pw = Plds[wave];
    const int wbase = wave * 2048;

    // ---- prologue: stage tile 0 into buf 0 ----
    {
        const char* gK = kbf + (tbase << 14);
        const char* gV = vbf + (tbase << 14);
        #pragma unroll
        for (int i = 0; i < 2; ++i) {
            gload16(gK + wbase + i * 1024 + lane * 16, &Klds[0][0] + wbase + i * 1024);
            gload16(gV + wbase + i * 1024 + lane * 16, &Vt[0][0]   + wbase + i * 1024);
        }
    }
    __syncthreads();

    for (int t = 0; t < ntiles; ++t) {
        const int buf = t & 1;
        // ---- issue prefetch of tile t+1 into buf^1 (drains at end-of-tile barrier) ----
        if (t + 1 < ntiles) {
            const char* gK = kbf + ((tbase + t + 1) << 14);
            const char* gV = vbf + ((tbase + t + 1) << 14);
            char* Kd = &Klds[buf ^ 1][0] + wbase;
            char* Vd = &Vt[buf ^ 1][0]   + wbase;
            #pragma unroll
            for (int i = 0; i < 2; ++i) {
                gload16(gK + wbase + i * 1024 + lane * 16, Kd + i * 1024);
                gload16(gV + wbase + i * 1024 + lane * 16, Vd + i * 1024);
            }
        }
        const char* Kb = &Klds[buf][0];
        const char* Vb = &Vt[buf][0];
        const int k0 = t * KVB;
        const bool lastt = (t == ntiles - 1);

        // ---- QK^T ----
        float sv[2][4][4];
        __builtin_amdgcn_s_setprio(1);
        #pragma unroll
        for (int ktile = 0; ktile < 4; ++ktile) {
            f32x4 sacc0 = (f32x4){0.f, 0.f, 0.f, 0.f};
            f32x4 sacc1 = (f32x4){0.f, 0.f, 0.f, 0.f};
            int row = ktile * 16 + q16;
            #pragma unroll
            for (int c = 0; c < 4; ++c) {
                bf16x8 kf = *(bf16x8*)(Kb + row * 256 +
                                       ((c * 64 + grp * 16) ^ ((row & 7) << 4)));
                sacc0 = __builtin_amdgcn_mfma_f32_16x16x32_bf16(qf[0][c], kf, sacc0, 0, 0, 0);
                sacc1 = __builtin_amdgcn_mfma_f32_16x16x32_bf16(qf[1][c], kf, sacc1, 0, 0, 0);
            }
            if (lastt) {
                int kpos = k0 + ktile * 16 + q16;
                #pragma unroll
                for (int r = 0; r < 4; ++r) {
                    int qp0 = pw0 + grp * 4 + r;
                    sv[0][ktile][r] = (kpos <= qp0)      ? sacc0[r] : -1e30f;
                    sv[1][ktile][r] = (kpos <= qp0 + 16) ? sacc1[r] : -1e30f;
                }
            } else {
                #pragma unroll
                for (int r = 0; r < 4; ++r) {
                    sv[0][ktile][r] = sacc0[r];
                    sv[1][ktile][r] = sacc1[r];
                }
            }
        }
        __builtin_amdgcn_s_setprio(0);

        // ---- per q-tile: softmax (deferred rescale + partial sums) then PV ----
        #pragma unroll
        for (int qt = 0; qt < 2; ++qt) {
            #pragma unroll
            for (int r = 0; r < 4; ++r) {
                float tm = fmaxf(fmaxf(fmaxf(sv[qt][0][r], sv[qt][1][r]),
                                 sv[qt][2][r]), sv[qt][3][r]);
                #pragma unroll
                for (int mm = 1; mm < 16; mm <<= 1) tm = fmaxf(tm, __shfl_xor(tm, mm));
                if (__any(tm > mrow[qt][r] + 8.0f)) {      // T13 defer (log2 units)
                    float newm = fmaxf(tm, mrow[qt][r]);
                    float scal = exp2f(mrow[qt][r] - newm);
                    mrow[qt][r] = newm;
                    lrow[qt][r] *= scal;
                    #pragma unroll
                    for (int n = 0; n < 8; ++n) oacc[qt][n][r] *= scal;
                }
                float m = mrow[qt][r];
                float ps = 0.f;
                int qrow = grp * 4 + r;
                #pragma unroll
                for (int kt2 = 0; kt2 < 4; ++kt2) {
                    float e = exp2f(sv[qt][kt2][r] - m);
                    ps += e;
                    *(unsigned short*)(Pw + qrow * 128 +
                        (((kt2 * 16 + q16) * 2) ^ ((qrow & 7) << 4))) = f2bf(e);
                }
                lrow[qt][r] += ps;     // per-lane partial; reduce in epilogue
            }

            __builtin_amdgcn_s_setprio(1);
            #pragma unroll
            for (int kt = 0; kt < 2; ++kt) {
                bf16x8 pf = *(bf16x8*)(Pw + q16 * 128 +
                                       ((kt * 64 + grp * 16) ^ ((q16 & 7) << 4)));
                #pragma unroll
                for (int n = 0; n < 8; ++n) {
                    int d = n * 16 + q16;
                    bf16x8 vv = *(bf16x8*)(Vb + d * 128 +
                                           ((kt * 64 + grp * 16) ^ ((d & 7) << 4)));
                    oacc[qt][n] = __builtin_amdgcn_mfma_f32_16x16x32_bf16(pf, vv, oacc[qt][n], 0, 0, 0);
                }
            }
            __builtin_amdgcn_s_setprio(0);
        }

        __syncthreads();   // single barrier: syncs LDS reuse + drains prefetch vmcnt
    }

    // ---- epilogue: reduce partial sums, normalize, store ----
    #pragma unroll
    for (int qt = 0; qt < 2; ++qt) {
        #pragma unroll
        for (int r = 0; r < 4; ++r) {
            float ls = lrow[qt][r];
            #pragma unroll
            for (int mm = 1; mm < 16; mm <<= 1) ls += __shfl_xor(ls, mm);
            float inv = 1.0f / ls;
            float* op = outg + ((size_t)(qw0 + qt * 16 + grp * 4 + r) * NH + head) * DHEAD;
            #pragma unroll
            for (int n = 0; n < 8; ++n) op[n * 16 + q16] = oacc[qt][n][r] * inv;
        }
    }
}

// ---------------- launch ----------------

extern "C" void kernel_launch(void* const* d_in, const int* in_sizes, int n_in,
                              void* d_out, int out_size, void* d_ws, size_t ws_size,
                              hipStream_t stream) {
    const float* q  = (const float*)d_in[0];
    const float* k  = (const float*)d_in[1];
    const float* v  = (const float*)d_in[2];
    const float* kc = (const float*)d_in[3];
    const float* vc = (const float*)d_in[4];
    const int* cu   = (const int*)d_in[5];
    const int* slot = (const int*)d_in[6];

    float* out    = (float*)d_out;
    float* kc_out = out + (size_t)T_TOT * NH * DHEAD;
    float* vc_out = kc_out + (size_t)NSLOTS * NKV * DHEAD;

    // bf16 tile scratch lives in the cache-output region; attn reads it,
    // then copy/scatter overwrite it with the real cache outputs.
    char* kbf = (char*)kc_out;
    char* vbf = (char*)vc_out;

    prep_kv<<<dim3(NTILES, NKV), dim3(256), 0, stream>>>(k, v, kbf, vbf);
    attn_kernel<<<dim3(512), dim3(512), 0, stream>>>(q, kbf, vbf, cu, out);

    copy_cache<<<dim3((NSLOTS * NKV * DHEAD / 4) / 256), dim3(256), 0, stream>>>(
        (const float4*)kc, (const float4*)vc, (float4*)kc_out, (float4*)vc_out);
    scatter_kv<<<dim3((T_TOT * NKV * DHEAD / 4) / 256), dim3(256), 0, stream>>>(
        (const float4*)k, (const float4*)v, slot, (float4*)kc_out, (float4*)vc_out);
}